// Round 1
// baseline (13391.354 us; speedup 1.0000x reference)
//
#include <hip/hip_runtime.h>
#include <hip/hip_bf16.h>

// GridCellRouter: N=4096*4096 cells, 16 iterations of
//   accum[idx[i]] += cur[i]   (scatter-add, random idx, duplicates)
//   cur[i] = accum[i] - cur[i]
// Grid-wide barrier needed between phases -> 2 kernels per iteration.
// accum lives in d_out; cur in d_ws.

#define N_CELLS (4096 * 4096)
#define ITERS 16

__global__ void gcr_init(const float* __restrict__ runoff,
                         float* __restrict__ accum,
                         float* __restrict__ cur, int n) {
    int i = (blockIdx.x * blockDim.x + threadIdx.x) * 4;
    if (i + 3 < n) {
        float4 r = *reinterpret_cast<const float4*>(runoff + i);
        *reinterpret_cast<float4*>(accum + i) = r;
        *reinterpret_cast<float4*>(cur + i) = r;
    } else {
        for (int k = i; k < n; ++k) {
            float r = runoff[k];
            accum[k] = r;
            cur[k] = r;
        }
    }
}

__global__ void gcr_scatter(const float* __restrict__ cur,
                            const int* __restrict__ idx,
                            float* __restrict__ accum, int n) {
    int i = (blockIdx.x * blockDim.x + threadIdx.x) * 4;
    if (i + 3 < n) {
        float4 c = *reinterpret_cast<const float4*>(cur + i);
        int4 d = *reinterpret_cast<const int4*>(idx + i);
        atomicAdd(accum + d.x, c.x);
        atomicAdd(accum + d.y, c.y);
        atomicAdd(accum + d.z, c.z);
        atomicAdd(accum + d.w, c.w);
    } else {
        for (int k = i; k < n; ++k) {
            atomicAdd(accum + idx[k], cur[k]);
        }
    }
}

__global__ void gcr_update(const float* __restrict__ accum,
                           float* __restrict__ cur, int n) {
    int i = (blockIdx.x * blockDim.x + threadIdx.x) * 4;
    if (i + 3 < n) {
        float4 a = *reinterpret_cast<const float4*>(accum + i);
        float4 c = *reinterpret_cast<const float4*>(cur + i);
        c.x = a.x - c.x;
        c.y = a.y - c.y;
        c.z = a.z - c.z;
        c.w = a.w - c.w;
        *reinterpret_cast<float4*>(cur + i) = c;
    } else {
        for (int k = i; k < n; ++k) {
            cur[k] = accum[k] - cur[k];
        }
    }
}

extern "C" void kernel_launch(void* const* d_in, const int* in_sizes, int n_in,
                              void* d_out, int out_size, void* d_ws, size_t ws_size,
                              hipStream_t stream) {
    const float* runoff = (const float*)d_in[0];
    const int* idx = (const int*)d_in[1];
    // d_in[2] is `iterations` (==16, compile-time constant for this problem)

    float* accum = (float*)d_out;   // N floats, final result
    float* cur = (float*)d_ws;      // N floats scratch

    const int n = N_CELLS;
    const int threads = 256;
    const int blocks4 = (n / 4 + threads - 1) / threads;  // 16384 blocks

    gcr_init<<<blocks4, threads, 0, stream>>>(runoff, accum, cur, n);

    for (int it = 0; it < ITERS; ++it) {
        gcr_scatter<<<blocks4, threads, 0, stream>>>(cur, idx, accum, n);
        gcr_update<<<blocks4, threads, 0, stream>>>(accum, cur, n);
    }
}